// Round 11
// baseline (124.620 us; speedup 1.0000x reference)
//
#include <hip/hip_runtime.h>

#define B_  8
#define TQ  256
#define TV  512
#define DD  256
#define ALGS 520  // alg row stride: quad-write banks {j,j+8,j+16,j+24} -> <=2-way = free

__device__ __forceinline__ float fast_exp2(float x) {
#if __has_builtin(__builtin_amdgcn_exp2f)
  return __builtin_amdgcn_exp2f(x);
#else
  return __exp2f(x);
#endif
}
__device__ __forceinline__ float fast_rcp(float x) {
#if __has_builtin(__builtin_amdgcn_rcpf)
  return __builtin_amdgcn_rcpf(x);
#else
  return 1.0f / x;
#endif
}

// ---------------------------------------------------------------------------
// Fused projections with EXP epilogue. THIS ROUND: keep the 768-block perfect
// balance (32x64 tiles, 3 blocks/CU exactly — R10's win) but restore the
// 4x4-per-thread fragment via 128 threads/block:
//   LDS traffic 3 B/fma -> 2 B/fma, instr density 10/8 -> 18/16 fma.
// 16 independent accumulators + double-buffered staging give in-wave ILP to
// cover the thinner 6 waves/CU. Same k-summation order (bitwise-identical).
// ---------------------------------------------------------------------------
__global__ __launch_bounds__(128) void proj_fused(
    const float* __restrict__ query, const float* __restrict__ value,
    const float* __restrict__ W1, const float* __restrict__ b1,
    const float* __restrict__ W2, const float* __restrict__ b2,
    float* __restrict__ qp, float* __restrict__ vp, float scale) {
  __shared__ float As[2][32][32];  // [p][k][m ^ sw(k)], 8 KB
  __shared__ float Bs[2][32][64];  // [p][k][n], 16 KB
  const int t  = threadIdx.x;      // 0..127
  const int rt = blockIdx.x;       // 0..191 row-tile (32 rows each)
  const int bn = blockIdx.y << 6;

  const float* A; const float* W; const float* bias; float* out; int row0;
  if (rt < 64) { row0 = rt << 5;        A = query; W = W1; bias = b1; out = qp; }
  else         { row0 = (rt - 64) << 5; A = value; W = W2; bias = b2; out = vp; }

  const int tx = t & 15, ty = t >> 4;          // col-quad 0..15, row-quad 0..7
  const int aar = t >> 2, aac = (t & 3) << 3;  // A: row 0..31, k-base {0,8,16,24}
  const int bbr = t >> 4, bbc = (t & 15) << 2; // B: k-row 0..7 (+8j), n-quad

  float4 ra0, ra1, rb[4];
  ra0 = *(const float4*)(A + (size_t)(row0 + aar) * DD + aac);
  ra1 = *(const float4*)(A + (size_t)(row0 + aar) * DD + aac + 4);
#pragma unroll
  for (int j = 0; j < 4; ++j)
    rb[j] = *(const float4*)(W + (size_t)(bbr + (j << 3)) * DD + bn + bbc);
  {
#pragma unroll
    for (int c = 0; c < 4; ++c) {
      const int k0_ = aac + c, k1_ = aac + 4 + c;
      As[0][k0_][aar ^ (((k0_ >> 2) & 7) << 2)] = (&ra0.x)[c];
      As[0][k1_][aar ^ (((k1_ >> 2) & 7) << 2)] = (&ra1.x)[c];
    }
#pragma unroll
    for (int j = 0; j < 4; ++j)
      *(float4*)&Bs[0][bbr + (j << 3)][bbc] = rb[j];
  }
  __syncthreads();

  float acc[4][4] = {{0.f,0.f,0.f,0.f},{0.f,0.f,0.f,0.f},
                     {0.f,0.f,0.f,0.f},{0.f,0.f,0.f,0.f}};
  int p = 0;

  for (int k0 = 0; k0 < 256; k0 += 32) {
    const bool more = (k0 + 32) < 256;
    if (more) {
      ra0 = *(const float4*)(A + (size_t)(row0 + aar) * DD + k0 + 32 + aac);
      ra1 = *(const float4*)(A + (size_t)(row0 + aar) * DD + k0 + 36 + aac);
#pragma unroll
      for (int j = 0; j < 4; ++j)
        rb[j] = *(const float4*)(W + (size_t)(k0 + 32 + bbr + (j << 3)) * DD + bn + bbc);
    }
#pragma unroll
    for (int k = 0; k < 32; ++k) {
      float4 aq = *(const float4*)&As[p][k][(ty << 2) ^ (((k >> 2) & 7) << 2)];
      float4 bq = *(const float4*)&Bs[p][k][tx << 2];
      acc[0][0] = fmaf(aq.x, bq.x, acc[0][0]); acc[0][1] = fmaf(aq.x, bq.y, acc[0][1]);
      acc[0][2] = fmaf(aq.x, bq.z, acc[0][2]); acc[0][3] = fmaf(aq.x, bq.w, acc[0][3]);
      acc[1][0] = fmaf(aq.y, bq.x, acc[1][0]); acc[1][1] = fmaf(aq.y, bq.y, acc[1][1]);
      acc[1][2] = fmaf(aq.y, bq.z, acc[1][2]); acc[1][3] = fmaf(aq.y, bq.w, acc[1][3]);
      acc[2][0] = fmaf(aq.z, bq.x, acc[2][0]); acc[2][1] = fmaf(aq.z, bq.y, acc[2][1]);
      acc[2][2] = fmaf(aq.z, bq.z, acc[2][2]); acc[2][3] = fmaf(aq.z, bq.w, acc[2][3]);
      acc[3][0] = fmaf(aq.w, bq.x, acc[3][0]); acc[3][1] = fmaf(aq.w, bq.y, acc[3][1]);
      acc[3][2] = fmaf(aq.w, bq.z, acc[3][2]); acc[3][3] = fmaf(aq.w, bq.w, acc[3][3]);
    }
    if (more) {
      const int q = p ^ 1;
#pragma unroll
      for (int c = 0; c < 4; ++c) {
        const int k0_ = aac + c, k1_ = aac + 4 + c;
        As[q][k0_][aar ^ (((k0_ >> 2) & 7) << 2)] = (&ra0.x)[c];
        As[q][k1_][aar ^ (((k1_ >> 2) & 7) << 2)] = (&ra1.x)[c];
      }
#pragma unroll
      for (int j = 0; j < 4; ++j)
        *(float4*)&Bs[q][bbr + (j << 3)][bbc] = rb[j];
      __syncthreads();
      p = q;
    }
  }

  float4 bvv = *(const float4*)&bias[bn + (tx << 2)];
#pragma unroll
  for (int r = 0; r < 4; ++r) {
    float4 o;
    o.x = fast_exp2(scale * (acc[r][0] + bvv.x));
    o.y = fast_exp2(scale * (acc[r][1] + bvv.y));
    o.z = fast_exp2(scale * (acc[r][2] + bvv.z));
    o.w = fast_exp2(scale * (acc[r][3] + bvv.w));
    *(float4*)(out + (size_t)(row0 + (ty << 2) + r) * DD + bn + (tx << 2)) = o;
  }
}

// ---------------------------------------------------------------------------
// Fused score + softmax + context + concat + transposed alignment.
// R2 monolith VERBATIM — best measured attn (45.4-52.2 us band, ±7 noise).
// R3-R8 established its plateau is structural (ILP, blocks, waves, splits
// all neutral/worse; R8: occupancy 62% at same duration -> not latency-bound).
// ---------------------------------------------------------------------------
__global__ __launch_bounds__(512, 4) void attn_mono(
    const float* __restrict__ qp, const float* __restrict__ vp,
    const float* __restrict__ value, const float* __restrict__ query,
    float* __restrict__ out1, float* __restrict__ out2) {
  __shared__ float qs[4 * 256];
  __shared__ float alg[4 * ALGS];
  __shared__ float ctxp[8][4][256];

  const int t    = threadIdx.x;
  const int lane = t & 63;
  const int wv   = t >> 6;
  const int jj   = lane >> 2;
  const int dq   = lane & 3;
  const int bb   = blockIdx.x & 7;
  const int i0   = (blockIdx.x >> 3) << 2;

  const float* vpb = vp + (size_t)bb * TV * DD;
  const float* qb  = qp + (size_t)(bb * TQ + i0) * DD;

  if (t < 256) {
    const int qi = t >> 6, qc = (t & 63) << 2;
    *(float4*)&qs[qi * 256 + qc] = *(const float4*)(qb + (size_t)qi * DD + qc);
  }
  __syncthreads();

  const int jb = (wv << 4) + jj;
  const float* vr0 = vpb + (size_t)jb * DD + (dq << 2);
  const float* vr1 = vr0 + 128 * DD;
  const float* vr2 = vr0 + 256 * DD;
  const float* vr3 = vr0 + 384 * DD;
  const float* qlane = qs + (dq << 2);

  float acc[4][4] = {{0.f,0.f,0.f,0.f},{0.f,0.f,0.f,0.f},
                     {0.f,0.f,0.f,0.f},{0.f,0.f,0.f,0.f}};

#pragma unroll 4
  for (int k = 0; k < 16; ++k) {
    const int doff = k << 4;
    float4 q0 = *(const float4*)(qlane + 0 * 256 + doff);
    float4 q1 = *(const float4*)(qlane + 1 * 256 + doff);
    float4 q2 = *(const float4*)(qlane + 2 * 256 + doff);
    float4 q3 = *(const float4*)(qlane + 3 * 256 + doff);
#pragma unroll
    for (int jg = 0; jg < 4; ++jg) {
      const float* vrp = (jg == 0) ? vr0 : (jg == 1) ? vr1 : (jg == 2) ? vr2 : vr3;
      float4 v4 = *(const float4*)(vrp + doff);
#pragma unroll
      for (int i = 0; i < 4; ++i) {
        const float4 q4 = (i == 0) ? q0 : (i == 1) ? q1 : (i == 2) ? q2 : q3;
        float a = q4.x * v4.x, b = q4.y * v4.y;
        float c = q4.z * v4.z, d = q4.w * v4.w;
        float sab = a + b,  scd = c + d;
        float Q1 = fmaf(a, b, sab + 1.f);
        float Q2 = fmaf(c, d, scd + 1.f);
        float N  = fmaf(scd + 2.f, Q1, (sab + 2.f) * Q2);
        acc[i][jg] = fmaf(N, fast_rcp(Q1 * Q2), acc[i][jg]);
      }
    }
  }

#pragma unroll
  for (int i = 0; i < 4; ++i)
#pragma unroll
    for (int jg = 0; jg < 4; ++jg) {
      acc[i][jg] += __shfl_xor(acc[i][jg], 1, 64);
      acc[i][jg] += __shfl_xor(acc[i][jg], 2, 64);
    }
#pragma unroll
  for (int jg = 0; jg < 4; ++jg) {
    float x = (dq == 0) ? acc[0][jg] : (dq == 1) ? acc[1][jg]
            : (dq == 2) ? acc[2][jg] : acc[3][jg];
    alg[dq * ALGS + (jg << 7) + jb] = x;
  }

  const int f4 = (t & 63) << 2;
  const int s  = t >> 6;
  const float* vb  = value + (size_t)bb * TV * DD;
  const float* vsp = vb + (size_t)(s << 6) * DD + f4;

  float4 pv0 = *(const float4*)(vsp + 0 * DD);
  float4 pv1 = *(const float4*)(vsp + 1 * DD);
  float4 pv2 = *(const float4*)(vsp + 2 * DD);
  float4 pv3 = *(const float4*)(vsp + 3 * DD);

  __syncthreads();

  if (wv < 4) {
    float sv[8];
#pragma unroll
    for (int c = 0; c < 8; ++c) sv[c] = alg[wv * ALGS + (c << 6) + lane];
    float mn = sv[0];
#pragma unroll
    for (int c = 1; c < 8; ++c) mn = fminf(mn, sv[c]);
#pragma unroll
    for (int m = 1; m < 64; m <<= 1) mn = fminf(mn, __shfl_xor(mn, m, 64));

    const float CC = 2.8853900817779268f;
    float p[8];
    float sum = 0.f;
#pragma unroll
    for (int c = 0; c < 8; ++c) { p[c] = fast_exp2(CC * (mn - sv[c])); sum += p[c]; }
#pragma unroll
    for (int m = 1; m < 64; m <<= 1) sum += __shfl_xor(sum, m, 64);
    const float inv = fast_rcp(sum);
#pragma unroll
    for (int c = 0; c < 8; ++c) alg[wv * ALGS + (c << 6) + lane] = p[c] * inv;
  }
  __syncthreads();

  {
    const int j = t;
    float4 av = make_float4(alg[j], alg[ALGS + j], alg[2 * ALGS + j], alg[3 * ALGS + j]);
    *(float4*)(out2 + (size_t)(bb * TV + j) * TQ + i0) = av;
  }

  float c4[4][4] = {{0.f,0.f,0.f,0.f},{0.f,0.f,0.f,0.f},
                    {0.f,0.f,0.f,0.f},{0.f,0.f,0.f,0.f}};
  const int jbase = s << 6;
  {
#pragma unroll
    for (int i = 0; i < 4; ++i) {
      float4 ai = *(const float4*)&alg[i * ALGS + jbase];
      c4[i][0] = fmaf(ai.x, pv0.x, c4[i][0]); c4[i][1] = fmaf(ai.x, pv0.y, c4[i][1]);
      c4[i][2] = fmaf(ai.x, pv0.z, c4[i][2]); c4[i][3] = fmaf(ai.x, pv0.w, c4[i][3]);
      c4[i][0] = fmaf(ai.y, pv1.x, c4[i][0]); c4[i][1] = fmaf(ai.y, pv1.y, c4[i][1]);
      c4[i][2] = fmaf(ai.y, pv1.z, c4[i][2]); c4[i][3] = fmaf(ai.y, pv1.w, c4[i][3]);
      c4[i][0] = fmaf(ai.z, pv2.x, c4[i][0]); c4[i][1] = fmaf(ai.z, pv2.y, c4[i][1]);
      c4[i][2] = fmaf(ai.z, pv2.z, c4[i][2]); c4[i][3] = fmaf(ai.z, pv2.w, c4[i][3]);
      c4[i][0] = fmaf(ai.w, pv3.x, c4[i][0]); c4[i][1] = fmaf(ai.w, pv3.y, c4[i][1]);
      c4[i][2] = fmaf(ai.w, pv3.z, c4[i][2]); c4[i][3] = fmaf(ai.w, pv3.w, c4[i][3]);
    }
  }
#pragma unroll 4
  for (int u = 4; u < 64; u += 4) {
    float4 v0 = *(const float4*)(vsp + (size_t)(u + 0) * DD);
    float4 v1 = *(const float4*)(vsp + (size_t)(u + 1) * DD);
    float4 v2 = *(const float4*)(vsp + (size_t)(u + 2) * DD);
    float4 v3 = *(const float4*)(vsp + (size_t)(u + 3) * DD);
#pragma unroll
    for (int i = 0; i < 4; ++i) {
      float4 ai = *(const float4*)&alg[i * ALGS + jbase + u];
      c4[i][0] = fmaf(ai.x, v0.x, c4[i][0]); c4[i][1] = fmaf(ai.x, v0.y, c4[i][1]);
      c4[i][2] = fmaf(ai.x, v0.z, c4[i][2]); c4[i][3] = fmaf(ai.x, v0.w, c4[i][3]);
      c4[i][0] = fmaf(ai.y, v1.x, c4[i][0]); c4[i][1] = fmaf(ai.y, v1.y, c4[i][1]);
      c4[i][2] = fmaf(ai.y, v1.z, c4[i][2]); c4[i][3] = fmaf(ai.y, v1.w, c4[i][3]);
      c4[i][0] = fmaf(ai.z, v2.x, c4[i][0]); c4[i][1] = fmaf(ai.z, v2.y, c4[i][1]);
      c4[i][2] = fmaf(ai.z, v2.z, c4[i][2]); c4[i][3] = fmaf(ai.z, v2.w, c4[i][3]);
      c4[i][0] = fmaf(ai.w, v3.x, c4[i][0]); c4[i][1] = fmaf(ai.w, v3.y, c4[i][1]);
      c4[i][2] = fmaf(ai.w, v3.z, c4[i][2]); c4[i][3] = fmaf(ai.w, v3.w, c4[i][3]);
    }
  }
#pragma unroll
  for (int i = 0; i < 4; ++i)
    *(float4*)&ctxp[s][i][f4] = make_float4(c4[i][0], c4[i][1], c4[i][2], c4[i][3]);
  __syncthreads();

  const float* qg = query + (size_t)(bb * TQ + i0) * DD;
  float* o = out1 + (size_t)(bb * TQ + i0) * (2 * DD);
#pragma unroll
  for (int it = 0; it < 2; ++it) {
    const int slot = t + (it << 9);
    const int ri = slot >> 8;
    const int ff = slot & 255;
    float sum = 0.f;
#pragma unroll
    for (int ss = 0; ss < 8; ++ss) sum += ctxp[ss][ri][ff];
    o[ri * 512 + ff] = sum;
    o[ri * 512 + 256 + ff] = qg[ri * DD + ff];
  }
}

// ---------------------------------------------------------------------------
extern "C" void kernel_launch(void* const* d_in, const int* in_sizes, int n_in,
                              void* d_out, int out_size, void* d_ws, size_t ws_size,
                              hipStream_t stream) {
  const float* query = (const float*)d_in[0];  // [8,256,256]
  const float* value = (const float*)d_in[1];  // [8,512,256]
  const float* W1    = (const float*)d_in[2];  // [256,256]
  const float* b1    = (const float*)d_in[3];  // [256]
  const float* W2    = (const float*)d_in[4];  // [256,256]
  const float* b2    = (const float*)d_in[5];  // [256]

  float* out1 = (float*)d_out;                     // context concat [8,256,512]
  float* out2 = out1 + (size_t)B_ * TQ * 2 * DD;   // alignment_t   [8,512,256]

  float* qp = (float*)d_ws;                        // Eq: 2048*256 floats
  float* vp = qp + (size_t)B_ * TQ * DD;           // Ev: 4096*256 floats

  const float SC = 2.8853900817779268f;  // 2*log2(e): exp(2x) = exp2(SC*x)

  proj_fused<<<dim3(192, 4), 128, 0, stream>>>(query, value, W1, b1, W2, b2, qp, vp, SC);
  attn_mono<<<dim3(B_ * (TQ / 4)), 512, 0, stream>>>(qp, vp, value, query, out1, out2);
}